// Round 1
// baseline (1173.550 us; speedup 1.0000x reference)
//
#include <hip/hip_runtime.h>
#include <math.h>

#define BB 8
#define TT 4096
#define CC 64
#define HD 64
#define PADK 66   // row stride in floats: 66 -> bank stride 2 -> 2-way (free)

// ---------------- Kernel 1: QKV projection ----------------
// out rows = x row (64) dot W[h][:] for each h. Block handles 8 rows.
__global__ __launch_bounds__(256) void qkv_proj(
    const float* __restrict__ x,
    const float* __restrict__ Wk,
    const float* __restrict__ Wq,
    const float* __restrict__ Wv,
    float* __restrict__ qo, float* __restrict__ ko, float* __restrict__ vo)
{
    __shared__ float Wt[3][64][65];   // transposed, padded: Wt[m][c][h]
    __shared__ float xs[8][64];
    int tid = threadIdx.x;
    for (int i = tid; i < 64 * 64; i += 256) {
        int h = i >> 6, c = i & 63;
        Wt[0][c][h] = Wq[i];
        Wt[1][c][h] = Wk[i];
        Wt[2][c][h] = Wv[i];
    }
    long row0 = (long)blockIdx.x * 8;
    const float* xb = x + row0 * 64;
    for (int i = tid; i < 8 * 64; i += 256) xs[i >> 6][i & 63] = xb[i];
    __syncthreads();

    int r = tid >> 6;    // wave id 0..3 -> rows r and r+4
    int h = tid & 63;
    float aq0 = 0.f, ak0 = 0.f, av0 = 0.f, aq1 = 0.f, ak1 = 0.f, av1 = 0.f;
#pragma unroll
    for (int c = 0; c < 64; ++c) {
        float x0 = xs[r][c], x1 = xs[r + 4][c];
        float wq = Wt[0][c][h], wk = Wt[1][c][h], wv = Wt[2][c][h];
        aq0 += x0 * wq; ak0 += x0 * wk; av0 += x0 * wv;
        aq1 += x1 * wq; ak1 += x1 * wk; av1 += x1 * wv;
    }
    long o0 = (row0 + r) * 64 + h;
    long o1 = (row0 + r + 4) * 64 + h;
    qo[o0] = aq0; ko[o0] = ak0; vo[o0] = av0;
    qo[o1] = aq1; ko[o1] = ak1; vo[o1] = av1;
}

// ---------------- Kernel 2: causal flash attention (vector fp32) ----------------
// One wave per query row t; lanes partition the s axis within 64-row K/V tiles.
// Per-lane online softmax; wave-level combine at the end via shfl butterfly.
__global__ __launch_bounds__(256) void attn_fwd(
    const float* __restrict__ qg,
    const float* __restrict__ kg,
    const float* __restrict__ vg,
    float* __restrict__ outg)
{
    __shared__ float ks[64 * PADK];
    __shared__ float vs[64 * PADK];
    int tid = threadIdx.x;
    int lane = tid & 63;
    int wid = tid >> 6;
    int blk = blockIdx.x;
    int b = blk >> 10;            // / (TT/4)
    int t0 = (blk & 1023) * 4;
    int t = t0 + wid;

    // load q row (broadcast across lanes; L1-served)
    const float4* qrow = (const float4*)(qg + ((long)b * TT + t) * 64);
    float q[64];
#pragma unroll
    for (int i = 0; i < 16; ++i) {
        float4 f = qrow[i];
        q[4 * i + 0] = f.x; q[4 * i + 1] = f.y; q[4 * i + 2] = f.z; q[4 * i + 3] = f.w;
    }
    float o[64];
#pragma unroll
    for (int i = 0; i < 64; ++i) o[i] = 0.f;
    float mval = -INFINITY, lval = 0.f;

    int ntiles = (t0 >> 6) + 1;   // same for all 4 waves in block (t0 % 4 == 0)
    const float2* kbase = (const float2*)(kg + (long)b * TT * 64);
    const float2* vbase = (const float2*)(vg + (long)b * TT * 64);

    for (int it = 0; it < ntiles; ++it) {
        int s0 = it << 6;
        __syncthreads();   // protect LDS from previous iteration readers
        for (int i = tid; i < 64 * 32; i += 256) {
            int row = i >> 5, c2 = i & 31;
            *(float2*)&ks[row * PADK + c2 * 2] = kbase[(s0 + row) * 32 + c2];
            *(float2*)&vs[row * PADK + c2 * 2] = vbase[(s0 + row) * 32 + c2];
        }
        __syncthreads();

        int s = s0 + lane;
        const float2* kr = (const float2*)&ks[lane * PADK];
        float sc = 0.f;
#pragma unroll
        for (int c2 = 0; c2 < 32; ++c2) {
            float2 kk = kr[c2];
            sc += q[2 * c2] * kk.x;
            sc += q[2 * c2 + 1] * kk.y;
        }
        sc *= 0.125f;   // C^-0.5, C=64
        if (s <= t) {
            float mn = fmaxf(mval, sc);
            float fac = __expf(mval - mn);   // mval=-inf first time -> 0
            float p = __expf(sc - mn);
            lval = lval * fac + p;
            const float2* vr = (const float2*)&vs[lane * PADK];
#pragma unroll
            for (int c2 = 0; c2 < 32; ++c2) {
                float2 vv = vr[c2];
                o[2 * c2]     = o[2 * c2]     * fac + p * vv.x;
                o[2 * c2 + 1] = o[2 * c2 + 1] * fac + p * vv.y;
            }
            mval = mn;
        }
    }

    // ---- wave combine: merge 64 per-lane (m, l, o[]) partials ----
    float M = mval;
#pragma unroll
    for (int d = 1; d < 64; d <<= 1) M = fmaxf(M, __shfl_xor(M, d, 64));
    float wgt = __expf(mval - M);     // 0 for lanes that never saw a valid s
    float Lp = lval * wgt;
#pragma unroll
    for (int d = 1; d < 64; d <<= 1) Lp += __shfl_xor(Lp, d, 64);
#pragma unroll
    for (int c = 0; c < 64; ++c) {
        float vsum = o[c] * wgt;
#pragma unroll
        for (int d = 1; d < 64; d <<= 1) vsum += __shfl_xor(vsum, d, 64);
        o[c] = vsum;                  // all lanes now hold the full sum for c
    }
    float res = 0.f;
#pragma unroll
    for (int c = 0; c < 64; ++c) if (lane == c) res = o[c];
    outg[((long)b * TT + t) * 64 + lane] = res / Lp;
}

extern "C" void kernel_launch(void* const* d_in, const int* in_sizes, int n_in,
                              void* d_out, int out_size, void* d_ws, size_t ws_size,
                              hipStream_t stream) {
    const float* x  = (const float*)d_in[0];
    const float* Wk = (const float*)d_in[1];
    const float* Wq = (const float*)d_in[2];
    const float* Wv = (const float*)d_in[3];
    float* out = (float*)d_out;

    const long N = (long)BB * TT * HD;   // 2,097,152 elements per tensor
    float* ws = (float*)d_ws;            // needs 3*N*4 = 24 MB
    float* qb = ws;
    float* kb = ws + N;
    float* vb = ws + 2 * N;

    qkv_proj<<<BB * TT / 8, 256, 0, stream>>>(x, Wk, Wq, Wv, qb, kb, vb);
    attn_fwd<<<BB * TT / 4, 256, 0, stream>>>(qb, kb, vb, out);
}

// Round 2
// 178.172 us; speedup vs baseline: 6.5866x; 6.5866x over previous
//
#include <hip/hip_runtime.h>
#include <hip/hip_bf16.h>
#include <math.h>

#define BB 8
#define TT 4096
#define HD 64

typedef __attribute__((ext_vector_type(8))) short short8;
typedef __attribute__((ext_vector_type(4))) float f32x4;

__device__ __forceinline__ short f2bf(float f) {
    __hip_bfloat16 h = __float2bfloat16(f);
    return __builtin_bit_cast(short, h);
}

// ---------------- Kernel 1: QKV projection (fp32, unchanged) ----------------
__global__ __launch_bounds__(256) void qkv_proj(
    const float* __restrict__ x,
    const float* __restrict__ Wk,
    const float* __restrict__ Wq,
    const float* __restrict__ Wv,
    float* __restrict__ qo, float* __restrict__ ko, float* __restrict__ vo)
{
    __shared__ float Wt[3][64][65];
    __shared__ float xs[8][64];
    int tid = threadIdx.x;
    for (int i = tid; i < 64 * 64; i += 256) {
        int h = i >> 6, c = i & 63;
        Wt[0][c][h] = Wq[i];
        Wt[1][c][h] = Wk[i];
        Wt[2][c][h] = Wv[i];
    }
    long row0 = (long)blockIdx.x * 8;
    const float* xb = x + row0 * 64;
    for (int i = tid; i < 8 * 64; i += 256) xs[i >> 6][i & 63] = xb[i];
    __syncthreads();

    int r = tid >> 6;
    int h = tid & 63;
    float aq0 = 0.f, ak0 = 0.f, av0 = 0.f, aq1 = 0.f, ak1 = 0.f, av1 = 0.f;
#pragma unroll
    for (int c = 0; c < 64; ++c) {
        float x0 = xs[r][c], x1 = xs[r + 4][c];
        float wq = Wt[0][c][h], wk = Wt[1][c][h], wv = Wt[2][c][h];
        aq0 += x0 * wq; ak0 += x0 * wk; av0 += x0 * wv;
        aq1 += x1 * wq; ak1 += x1 * wk; av1 += x1 * wv;
    }
    long o0 = (row0 + r) * 64 + h;
    long o1 = (row0 + r + 4) * 64 + h;
    qo[o0] = aq0; ko[o0] = ak0; vo[o0] = av0;
    qo[o1] = aq1; ko[o1] = ak1; vo[o1] = av1;
}

// ---------------- Kernel 2: MFMA flash attention ----------------
// Block = 256 thr = 4 waves, QBLK=64 (wave owns 16 q-rows), KVBLK=64.
// mfma_f32_16x16x32_bf16. C/D layout: col=lane&15, row=4*(lane>>4)+reg.
// A layout: row=lane&15, k=8*(lane>>4)+e. B layout: col=lane&15, k=8*(lane>>4)+e.
__global__ __launch_bounds__(256) void attn_mfma(
    const float* __restrict__ qg, const float* __restrict__ kg,
    const float* __restrict__ vg, float* __restrict__ outg)
{
    __shared__ short kls[64 * 72];      // K[key][d], stride 72 bf16 (144B: 16B-aligned rows, banks spread)
    __shared__ short vls[64 * 64];      // V^T[d][s], 16B-block swizzle: blk ^ (d&7)
    __shared__ short pls[4][16 * 72];   // per-wave P[qrow][s], stride 72

    const int tid  = threadIdx.x;
    const int lane = tid & 63;
    const int w    = tid >> 6;
    const int g    = lane >> 4;   // k-group / row-group
    const int c    = lane & 15;   // frag row (A) / frag col (B, C/D)

    const int bi = blockIdx.x;
    const int qt = 63 - (bi >> 3);      // descending work order (LPT)
    const int b  = bi & 7;
    const int q0 = qt * 64;

    const long bbase = (long)b * TT * HD;

    // Q fragments (A-operand, register-resident): row q0+16w+c, k = 32*ksi+8g+e
    short8 qf[2];
    {
        const float* qp = qg + bbase + (long)(q0 + 16 * w + c) * HD + 8 * g;
#pragma unroll
        for (int ksi = 0; ksi < 2; ++ksi) {
            float4 f0 = *(const float4*)(qp + 32 * ksi);
            float4 f1 = *(const float4*)(qp + 32 * ksi + 4);
            short8 q8;
            q8[0] = f2bf(f0.x); q8[1] = f2bf(f0.y); q8[2] = f2bf(f0.z); q8[3] = f2bf(f0.w);
            q8[4] = f2bf(f1.x); q8[5] = f2bf(f1.y); q8[6] = f2bf(f1.z); q8[7] = f2bf(f1.w);
            qf[ksi] = q8;
        }
    }

    f32x4 oacc[4] = {};            // O acc, [nt] x 4 rows
    float m0[4], l0[4];
#pragma unroll
    for (int r = 0; r < 4; ++r) { m0[r] = -INFINITY; l0[r] = 0.f; }

    const int krow = tid >> 2, kseg = tid & 3;  // K staging: row, 16-float segment
    const int vd = tid & 63, vsg0 = tid >> 6;   // V staging: d column, s-block

    for (int it = 0; it <= qt; ++it) {
        const int s0 = it * 64;
        __syncthreads();
        // ---- stage K tile (row-major, fp32->bf16) ----
        {
            const float* kp = kg + bbase + (long)(s0 + krow) * HD + kseg * 16;
            float4 a0 = *(const float4*)(kp + 0);
            float4 a1 = *(const float4*)(kp + 4);
            float4 a2 = *(const float4*)(kp + 8);
            float4 a3 = *(const float4*)(kp + 12);
            short8 w0, w1;
            w0[0] = f2bf(a0.x); w0[1] = f2bf(a0.y); w0[2] = f2bf(a0.z); w0[3] = f2bf(a0.w);
            w0[4] = f2bf(a1.x); w0[5] = f2bf(a1.y); w0[6] = f2bf(a1.z); w0[7] = f2bf(a1.w);
            w1[0] = f2bf(a2.x); w1[1] = f2bf(a2.y); w1[2] = f2bf(a2.z); w1[3] = f2bf(a2.w);
            w1[4] = f2bf(a3.x); w1[5] = f2bf(a3.y); w1[6] = f2bf(a3.z); w1[7] = f2bf(a3.w);
            *(short8*)&kls[krow * 72 + kseg * 16 + 0] = w0;
            *(short8*)&kls[krow * 72 + kseg * 16 + 8] = w1;
        }
        // ---- stage V^T tile (transpose via coalesced column reads, swizzled write) ----
        {
#pragma unroll
            for (int h = 0; h < 2; ++h) {
                int sg = vsg0 + 4 * h;
                short8 vv;
#pragma unroll
                for (int j = 0; j < 8; ++j)
                    vv[j] = f2bf(vg[bbase + (long)(s0 + 8 * sg + j) * HD + vd]);
                *(short8*)&vls[64 * vd + 8 * (sg ^ (vd & 7))] = vv;
            }
        }
        __syncthreads();

        // ---- S = Q K^T (8 MFMA) ----
        f32x4 sv[4] = {};
#pragma unroll
        for (int nt = 0; nt < 4; ++nt) {
#pragma unroll
            for (int ksi = 0; ksi < 2; ++ksi) {
                short8 kf = *(const short8*)&kls[(16 * nt + c) * 72 + 32 * ksi + 8 * g];
                sv[nt] = __builtin_amdgcn_mfma_f32_16x16x32_bf16(qf[ksi], kf, sv[nt], 0, 0, 0);
            }
        }

        // ---- scale + causal mask (diagonal tile only) ----
        const int trow = q0 + 16 * w + 4 * g;   // + r
#pragma unroll
        for (int nt = 0; nt < 4; ++nt) {
#pragma unroll
            for (int r = 0; r < 4; ++r) {
                float s = sv[nt][r] * 0.125f;
                if (it == qt && (s0 + 16 * nt + c) > (trow + r)) s = -INFINITY;
                sv[nt][r] = s;
            }
        }

        // ---- online softmax (row = 4g+r, spread over 16 lanes x 4 nt) ----
        float pfac[4], rsum[4];
#pragma unroll
        for (int r = 0; r < 4; ++r) {
            float mx = fmaxf(fmaxf(sv[0][r], sv[1][r]), fmaxf(sv[2][r], sv[3][r]));
#pragma unroll
            for (int d = 1; d < 16; d <<= 1) mx = fmaxf(mx, __shfl_xor(mx, d, 64));
            float mn = fmaxf(m0[r], mx);
            pfac[r] = __expf(m0[r] - mn);
            m0[r] = mn;
        }
#pragma unroll
        for (int r = 0; r < 4; ++r) rsum[r] = 0.f;
        short* pw = &pls[w][0];
#pragma unroll
        for (int nt = 0; nt < 4; ++nt) {
#pragma unroll
            for (int r = 0; r < 4; ++r) {
                float p = __expf(sv[nt][r] - m0[r]);   // masked -> exp(-inf)=0
                rsum[r] += p;
                pw[(4 * g + r) * 72 + 16 * nt + c] = f2bf(p);
            }
        }
#pragma unroll
        for (int r = 0; r < 4; ++r) {
            float rs = rsum[r];
#pragma unroll
            for (int d = 1; d < 16; d <<= 1) rs += __shfl_xor(rs, d, 64);
            l0[r] = l0[r] * pfac[r] + rs;
        }
#pragma unroll
        for (int nt = 0; nt < 4; ++nt)
#pragma unroll
            for (int r = 0; r < 4; ++r) oacc[nt][r] *= pfac[r];

        // ---- O += P V (8 MFMA; P per-wave in LDS, V^T swizzled) ----
#pragma unroll
        for (int ksi = 0; ksi < 2; ++ksi) {
            short8 pa = *(const short8*)&pw[c * 72 + 32 * ksi + 8 * g];
#pragma unroll
            for (int nt = 0; nt < 4; ++nt) {
                int d = 16 * nt + c;
                short8 vf = *(const short8*)&vls[64 * d + 8 * ((4 * ksi + g) ^ (d & 7))];
                oacc[nt] = __builtin_amdgcn_mfma_f32_16x16x32_bf16(pa, vf, oacc[nt], 0, 0, 0);
            }
        }
    }

    // ---- epilogue: normalize and store fp32 ----
    float* op = outg + bbase + (long)(q0 + 16 * w + 4 * g) * HD + c;
#pragma unroll
    for (int nt = 0; nt < 4; ++nt)
#pragma unroll
        for (int r = 0; r < 4; ++r)
            op[(long)r * HD + 16 * nt] = oacc[nt][r] / l0[r];
}

extern "C" void kernel_launch(void* const* d_in, const int* in_sizes, int n_in,
                              void* d_out, int out_size, void* d_ws, size_t ws_size,
                              hipStream_t stream) {
    const float* x  = (const float*)d_in[0];
    const float* Wk = (const float*)d_in[1];
    const float* Wq = (const float*)d_in[2];
    const float* Wv = (const float*)d_in[3];
    float* out = (float*)d_out;

    const long N = (long)BB * TT * HD;
    float* ws = (float*)d_ws;
    float* qb = ws;
    float* kb = ws + N;
    float* vb = ws + 2 * N;

    qkv_proj<<<BB * TT / 8, 256, 0, stream>>>(x, Wk, Wq, Wv, qb, kb, vb);
    attn_mfma<<<BB * 64, 256, 0, stream>>>(qb, kb, vb, out);
}

// Round 3
// 141.280 us; speedup vs baseline: 8.3066x; 1.2611x over previous
//
#include <hip/hip_runtime.h>
#include <hip/hip_bf16.h>
#include <math.h>

#define BB 8
#define TT 4096
#define HD 64

typedef __attribute__((ext_vector_type(8))) short short8;
typedef __attribute__((ext_vector_type(4))) float f32x4;
typedef __attribute__((ext_vector_type(16))) float f32x16;
typedef __attribute__((ext_vector_type(2))) unsigned int uint2v;
typedef __attribute__((ext_vector_type(4))) unsigned int uint4v;

__device__ __forceinline__ unsigned short bfbits(float f) {
    return __builtin_bit_cast(unsigned short, __float2bfloat16(f));
}
__device__ __forceinline__ unsigned pack_bf2(float a, float b) {
    return (unsigned)bfbits(a) | ((unsigned)bfbits(b) << 16);
}

// ---------------- Kernel 1: QKV projection -> bf16 q,k and bf16 V^T ----------------
// Block: 256 thr, 64 t-rows. W staged once per block (fp32), fp32 accum,
// outputs rounded to bf16. V written transposed [b][d][t] via LDS buffer.
__global__ __launch_bounds__(256) void qkv_proj(
    const float* __restrict__ x,
    const float* __restrict__ Wk, const float* __restrict__ Wq, const float* __restrict__ Wv,
    unsigned short* __restrict__ qo, unsigned short* __restrict__ ko,
    unsigned short* __restrict__ vto)
{
    __shared__ float Wt[3][64][65];          // [m][c][h], 2-way bank alias (free)
    __shared__ float xs[64][64];
    __shared__ unsigned short vb[64][72];    // [h][t_local], stride 72 shorts (144B)

    const int tid = threadIdx.x;
    for (int i = tid; i < 64 * 64; i += 256) {
        int h = i >> 6, c = i & 63;
        Wt[0][c][h] = Wq[i];
        Wt[1][c][h] = Wk[i];
        Wt[2][c][h] = Wv[i];
    }
    const long row0 = (long)blockIdx.x * 64;
    const float* xb = x + row0 * 64;
    for (int i = tid; i < 64 * 64; i += 256) xs[i >> 6][i & 63] = xb[i];
    __syncthreads();

    const int w = tid >> 6, h = tid & 63;
    float aq[16], ak[16], av[16];
#pragma unroll
    for (int j = 0; j < 16; ++j) { aq[j] = 0.f; ak[j] = 0.f; av[j] = 0.f; }
#pragma unroll
    for (int c = 0; c < 64; ++c) {
        float wq = Wt[0][c][h], wk = Wt[1][c][h], wv = Wt[2][c][h];
#pragma unroll
        for (int j = 0; j < 16; ++j) {
            float xv = xs[4 * j + w][c];        // wave-uniform addr -> broadcast
            aq[j] += xv * wq; ak[j] += xv * wk; av[j] += xv * wv;
        }
    }
#pragma unroll
    for (int j = 0; j < 16; ++j) {
        int r = 4 * j + w;
        qo[(row0 + r) * 64 + h] = bfbits(aq[j]);
        ko[(row0 + r) * 64 + h] = bfbits(ak[j]);
        vb[h][r] = bfbits(av[j]);
    }
    __syncthreads();

    // transpose-out V: thread (h2, sg) writes 2 chunks of 8 t-values
    const int h2 = tid >> 2, sg = tid & 3;
    const int b = (int)(row0 >> 12);
    const int tloc = (int)(row0 & 4095);
#pragma unroll
    for (int cc = 0; cc < 2; ++cc) {
        int sgi = sg + 4 * cc;
        const unsigned long long* vp = (const unsigned long long*)&vb[h2][8 * sgi];
        unsigned long long lo = vp[0], hi2 = vp[1];
        uint4v o;
        o[0] = (unsigned)lo; o[1] = (unsigned)(lo >> 32);
        o[2] = (unsigned)hi2; o[3] = (unsigned)(hi2 >> 32);
        *(uint4v*)(vto + ((long)b * 64 + h2) * 4096 + tloc + 8 * sgi) = o;
    }
}

// ---------------- Kernel 2: MFMA flash attention, swapped-operand 32x32 ----------------
// Block = 4 waves, wave owns 32 q-rows (QBLK=128/block), KVBLK=64.
// S^T = mfma(K, Q): col = q = lane&31 -> lane-local online softmax.
// P->A-frag via cvt-pack + permlane32_swap (T12). O^T = mfma(V^T, P).
// C/D layout: col=lane&31, row=(reg&3)+8*(reg>>2)+4*(lane>>5)  [m74/m101].
__global__ __launch_bounds__(256) void attn_mfma(
    const unsigned short* __restrict__ qg,   // [b][t][64] bf16
    const unsigned short* __restrict__ kg,   // [b][t][64] bf16
    const unsigned short* __restrict__ vtg,  // [b][64][4096] bf16
    float* __restrict__ outg)
{
    __shared__ short kls[64 * 64];   // K[s][d], 16B-block XOR swizzle: blk ^ (row&7)
    __shared__ short vls[64 * 64];   // V^T[d][s], same swizzle

    const int tid = threadIdx.x;
    const int l = tid & 63;
    const int w = tid >> 6;
    const int q = l & 31;
    const int hi = l >> 5;

    const int qt = 31 - (blockIdx.x >> 3);   // descending work (LPT)
    const int b = blockIdx.x & 7;
    const int q0b = qt * 128;
    const int q0w = q0b + 32 * w;
    const int qr = q0w + q;

    // Q fragments (B-operand): col=q, k = 16*ki + 8*hi + e
    const unsigned short* qb = qg + ((long)b * TT + qr) * HD;
    short8 qf[4];
#pragma unroll
    for (int ki = 0; ki < 4; ++ki)
        qf[ki] = *(const short8*)(qb + 16 * ki + 8 * hi);

    f32x16 oacc[2] = {};
    float m = -INFINITY, lsum = 0.f;

    const int lastw = (q0w + 31) >> 6;        // this wave's last KV tile
    const int ntile = 2 * qt + 2;             // block's KV tiles

    const unsigned short* kbase = kg + (long)b * TT * HD;
    const unsigned short* vbase = vtg + (long)b * HD * TT;

    // staging: slot = tid + 256*i -> row=slot>>3, blk=slot&7 (conflict-free, coalesced)
    short8 kst[2], vst[2];
#pragma unroll
    for (int i = 0; i < 2; ++i) {
        int slot = tid + 256 * i;
        int row = slot >> 3, bl = slot & 7;
        kst[i] = *(const short8*)(kbase + (long)row * HD + 8 * bl);
        vst[i] = *(const short8*)(vbase + (long)row * TT + 8 * bl);
    }

    for (int it = 0; it < ntile; ++it) {
        const int s0 = it * 64;
        __syncthreads();
#pragma unroll
        for (int i = 0; i < 2; ++i) {
            int slot = tid + 256 * i;
            int row = slot >> 3, bl = slot & 7;
            *(short8*)&kls[row * 64 + 8 * (bl ^ (row & 7))] = kst[i];
            *(short8*)&vls[row * 64 + 8 * (bl ^ (row & 7))] = vst[i];
        }
        __syncthreads();

        // prefetch next tile (overlaps with compute below — T14)
        if (it + 1 < ntile) {
            const int s1 = s0 + 64;
#pragma unroll
            for (int i = 0; i < 2; ++i) {
                int slot = tid + 256 * i;
                int row = slot >> 3, bl = slot & 7;
                kst[i] = *(const short8*)(kbase + (long)(s1 + row) * HD + 8 * bl);
                vst[i] = *(const short8*)(vbase + (long)row * TT + s1 + 8 * bl);
            }
        }

        if (s0 > q0w + 31) continue;   // wave past causal range; barriers still met above

        // skip fully-masked upper kk-half on the diagonal tile
        const int nkt = (it == lastw && (q0w & 32) == 0) ? 1 : 2;

        // ---- S^T = K Q^T (A=K from LDS, B=Q regs) ----
        f32x16 sacc[2] = {};
#pragma unroll
        for (int kt = 0; kt < 2; ++kt) {
            if (kt < nkt) {
#pragma unroll
                for (int ki = 0; ki < 4; ++ki) {
                    int row = 32 * kt + q;
                    short8 kf = *(const short8*)&kls[row * 64 + 8 * ((2 * ki + hi) ^ (row & 7))];
                    sacc[kt] = __builtin_amdgcn_mfma_f32_32x32x16_bf16(kf, qf[ki], sacc[kt], 0, 0, 0);
                }
            }
        }

        // ---- scale + causal mask + lane-local max ----
        float pmax = -INFINITY;
#pragma unroll
        for (int kt = 0; kt < 2; ++kt) {
            if (kt >= nkt) continue;
#pragma unroll
            for (int r = 0; r < 16; ++r) {
                float s = sacc[kt][r] * 0.125f;
                if (it == lastw) {
                    int kkg = s0 + 32 * kt + (r & 3) + 8 * (r >> 2) + 4 * hi;
                    if (kkg > qr) s = -INFINITY;
                }
                sacc[kt][r] = s;
                pmax = fmaxf(pmax, s);
            }
        }
        pmax = fmaxf(pmax, __shfl_xor(pmax, 32, 64));
        const float mn = fmaxf(m, pmax);
        const float fac = __expf(m - mn);
        m = mn;

        // ---- exp + pack to bf16 pairs (u_lo/u_hi per 8-kk run) ----
        float rsum = 0.f;
        unsigned ulo[8], uhi[8];
#pragma unroll
        for (int kt = 0; kt < 2; ++kt) {
#pragma unroll
            for (int jj = 0; jj < 4; ++jj) {
                float p0 = 0.f, p1 = 0.f, p2 = 0.f, p3 = 0.f;
                if (kt < nkt) {
                    p0 = __expf(sacc[kt][4 * jj + 0] - mn);
                    p1 = __expf(sacc[kt][4 * jj + 1] - mn);
                    p2 = __expf(sacc[kt][4 * jj + 2] - mn);
                    p3 = __expf(sacc[kt][4 * jj + 3] - mn);
                    rsum += (p0 + p1) + (p2 + p3);
                }
                ulo[4 * kt + jj] = pack_bf2(p0, p1);
                uhi[4 * kt + jj] = pack_bf2(p2, p3);
            }
        }
        rsum += __shfl_xor(rsum, 32, 64);
        lsum = lsum * fac + rsum;
        oacc[0] *= fac;
        oacc[1] *= fac;

        // ---- O^T += V^T P  (A=V^T from LDS, B=P via permlane32_swap) ----
        const int nks = 2 * nkt;
#pragma unroll
        for (int ks = 0; ks < 4; ++ks) {
            if (ks >= nks) continue;
            uint2v rlo = __builtin_amdgcn_permlane32_swap(ulo[2 * ks], ulo[2 * ks + 1], false, false);
            uint2v rhi = __builtin_amdgcn_permlane32_swap(uhi[2 * ks], uhi[2 * ks + 1], false, false);
            uint4v paw;
            paw[0] = rlo[0]; paw[1] = rhi[0]; paw[2] = rlo[1]; paw[3] = rhi[1];
            short8 pa = __builtin_bit_cast(short8, paw);
#pragma unroll
            for (int dt = 0; dt < 2; ++dt) {
                int row = 32 * dt + q;
                short8 vf = *(const short8*)&vls[row * 64 + 8 * ((2 * ks + hi) ^ (row & 7))];
                oacc[dt] = __builtin_amdgcn_mfma_f32_32x32x16_bf16(vf, pa, oacc[dt], 0, 0, 0);
            }
        }
    }

    // ---- epilogue: normalize, store fp32 (lane owns row qr; d = 32dt+8jj+4hi+0..3) ----
    const float inv = 1.f / lsum;
    float* op = outg + ((long)b * TT + qr) * HD;
#pragma unroll
    for (int dt = 0; dt < 2; ++dt) {
#pragma unroll
        for (int jj = 0; jj < 4; ++jj) {
            f32x4 o4;
            o4[0] = oacc[dt][4 * jj + 0] * inv;
            o4[1] = oacc[dt][4 * jj + 1] * inv;
            o4[2] = oacc[dt][4 * jj + 2] * inv;
            o4[3] = oacc[dt][4 * jj + 3] * inv;
            *(f32x4*)(op + 32 * dt + 8 * jj + 4 * hi) = o4;
        }
    }
}

extern "C" void kernel_launch(void* const* d_in, const int* in_sizes, int n_in,
                              void* d_out, int out_size, void* d_ws, size_t ws_size,
                              hipStream_t stream) {
    const float* x  = (const float*)d_in[0];
    const float* Wk = (const float*)d_in[1];
    const float* Wq = (const float*)d_in[2];
    const float* Wv = (const float*)d_in[3];
    float* out = (float*)d_out;

    const long N = (long)BB * TT * HD;          // 2,097,152
    unsigned short* q16 = (unsigned short*)d_ws;     // 4 MB
    unsigned short* k16 = q16 + N;                   // 4 MB
    unsigned short* vt16 = k16 + N;                  // 4 MB (transposed V)

    qkv_proj<<<BB * TT / 64, 256, 0, stream>>>(x, Wk, Wq, Wv, q16, k16, vt16);
    attn_mfma<<<32 * BB, 256, 0, stream>>>(q16, k16, vt16, out);
}

// Round 4
// 84.072 us; speedup vs baseline: 13.9588x; 1.6805x over previous
//
#include <hip/hip_runtime.h>
#include <hip/hip_bf16.h>
#include <math.h>

#define BB 8
#define TT 4096
#define HD 64

typedef __attribute__((ext_vector_type(8))) short short8;
typedef __attribute__((ext_vector_type(4))) float f32x4;
typedef __attribute__((ext_vector_type(16))) float f32x16;
typedef __attribute__((ext_vector_type(2))) unsigned int uint2v;

__device__ __forceinline__ unsigned short bfbits(float f) {
    return __builtin_bit_cast(unsigned short, __float2bfloat16(f));
}
__device__ __forceinline__ unsigned pack_bf2(float a, float b) {
    return (unsigned)bfbits(a) | ((unsigned)bfbits(b) << 16);
}
__device__ __forceinline__ float bf2f(unsigned short u) {
    unsigned v = (unsigned)u << 16;
    return __builtin_bit_cast(float, v);
}
__device__ __forceinline__ short8 cvt8(float4 a, float4 b, float sc) {
    short8 s;
    s[0] = (short)bfbits(a.x * sc); s[1] = (short)bfbits(a.y * sc);
    s[2] = (short)bfbits(a.z * sc); s[3] = (short)bfbits(a.w * sc);
    s[4] = (short)bfbits(b.x * sc); s[5] = (short)bfbits(b.y * sc);
    s[6] = (short)bfbits(b.z * sc); s[7] = (short)bfbits(b.w * sc);
    return s;
}

// ---------------- Kernel 1: MFMA QKV projection ----------------
// Block: 256 thr (4 waves), 128 t-rows. C[t,h'] = x·W'^T via mfma(A=x, B=W').
// W' rows: 0..63 Wq (pre-scaled by 0.125), 64..127 Wk, 128..191 Wv.
// V computed swapped (A=Wv, B=x) -> C'[h][t]: lane owns t-col -> coalesced
// transposed stores. q,k bounced through LDS for vectorized row stores.
__global__ __launch_bounds__(256) void qkv_proj_mfma(
    const float* __restrict__ x,
    const float* __restrict__ Wk, const float* __restrict__ Wq, const float* __restrict__ Wv,
    unsigned short* __restrict__ qo, unsigned short* __restrict__ ko,
    unsigned short* __restrict__ vto)
{
    __shared__ short lds[20480];          // 40KB: stage {xls 8192, wls 12288} / bounce {cb 17408}
    short* xls = lds;
    short* wls = lds + 8192;

    const int tid = threadIdx.x;
    const int l = tid & 63, w = tid >> 6;
    const int hi = l >> 5, c31 = l & 31;
    const long t0 = (long)blockIdx.x * 128;
    const int b = (int)(t0 >> 12);
    const int tl0 = (int)(t0 & 4095);

    // stage x tile (128x64 fp32 -> bf16, XOR-swizzled)
#pragma unroll
    for (int i = 0; i < 4; ++i) {
        int slot = tid + 256 * i;
        int row = slot >> 3, bl = slot & 7;
        const float* xp = x + (t0 + row) * 64 + 8 * bl;
        float4 a = *(const float4*)xp;
        float4 bq = *(const float4*)(xp + 4);
        *(short8*)&xls[row * 64 + 8 * (bl ^ (row & 7))] = cvt8(a, bq, 1.f);
    }
    // stage W' (192x64), Wq scaled by 0.125
#pragma unroll
    for (int i = 0; i < 6; ++i) {
        int slot = tid + 256 * i;
        int row = slot >> 3, bl = slot & 7;
        const float* wp;
        float sc;
        if (row < 64)       { wp = Wq + row * 64;        sc = 0.125f; }
        else if (row < 128) { wp = Wk + (row - 64) * 64; sc = 1.f; }
        else                { wp = Wv + (row - 128) * 64; sc = 1.f; }
        wp += 8 * bl;
        float4 a = *(const float4*)wp;
        float4 bq = *(const float4*)(wp + 4);
        *(short8*)&wls[row * 64 + 8 * (bl ^ (row & 7))] = cvt8(a, bq, sc);
    }
    __syncthreads();

    // x fragments: A-rows (q,k) AND B-cols (v) = rows 32w + c31
    short8 xf[4];
#pragma unroll
    for (int ki = 0; ki < 4; ++ki) {
        int row = 32 * w + c31;
        xf[ki] = *(const short8*)&xls[row * 64 + 8 * ((2 * ki + hi) ^ (row & 7))];
    }
    f32x16 cqk[4] = {};   // nt: h' tiles 0..3 (q0,q1,k0,k1)
#pragma unroll
    for (int nt = 0; nt < 4; ++nt) {
#pragma unroll
        for (int ki = 0; ki < 4; ++ki) {
            int row = 32 * nt + c31;
            short8 wf = *(const short8*)&wls[row * 64 + 8 * ((2 * ki + hi) ^ (row & 7))];
            cqk[nt] = __builtin_amdgcn_mfma_f32_32x32x16_bf16(xf[ki], wf, cqk[nt], 0, 0, 0);
        }
    }
    f32x16 cv[2] = {};    // swapped: C'[h][t]
#pragma unroll
    for (int rt = 0; rt < 2; ++rt) {
#pragma unroll
        for (int ki = 0; ki < 4; ++ki) {
            int row = 128 + 32 * rt + c31;
            short8 wf = *(const short8*)&wls[row * 64 + 8 * ((2 * ki + hi) ^ (row & 7))];
            cv[rt] = __builtin_amdgcn_mfma_f32_32x32x16_bf16(wf, xf[ki], cv[rt], 0, 0, 0);
        }
    }

    // V: direct coalesced transposed stores (lane owns t-col = tl0 + 32w + c31)
#pragma unroll
    for (int rt = 0; rt < 2; ++rt) {
#pragma unroll
        for (int r = 0; r < 16; ++r) {
            int h = 32 * rt + (r & 3) + 8 * (r >> 2) + 4 * hi;
            vto[((long)b * 64 + h) * 4096 + tl0 + 32 * w + c31] = bfbits(cv[rt][r]);
        }
    }

    __syncthreads();   // done reading xls/wls
    short* cb = lds;   // bounce: [t][h'], stride 136 shorts
#pragma unroll
    for (int nt = 0; nt < 4; ++nt) {
#pragma unroll
        for (int r = 0; r < 16; ++r) {
            int trow = 32 * w + (r & 3) + 8 * (r >> 2) + 4 * hi;
            cb[trow * 136 + 32 * nt + c31] = (short)bfbits(cqk[nt][r]);
        }
    }
    __syncthreads();
    {
        int row = tid >> 1, seg = tid & 1;
        const short8* cp = (const short8*)&cb[row * 136 + seg * 64];
        unsigned short* dst = (seg == 0 ? qo : ko) + (t0 + row) * 64;
#pragma unroll
        for (int i = 0; i < 8; ++i) ((short8*)dst)[i] = cp[i];
    }
}

// ---------------- Kernel 2: MFMA flash attention, split-s ----------------
// Grid = 8b x 80 chunks. Chunk = 16 KV-tiles (1024 s). Q-block 128 rows,
// 4 waves x 32 q-rows, swapped QK^T (lane-local softmax), permlane P->A.
// nc==1 (qt<=7): direct out. Else bf16 partial O' + fp32 (m,l) for combine.
__global__ __launch_bounds__(256) void attn_mfma(
    const unsigned short* __restrict__ qg,
    const unsigned short* __restrict__ kg,
    const unsigned short* __restrict__ vtg,
    unsigned short* __restrict__ Opart,
    float2* __restrict__ ml,
    float* __restrict__ outg)
{
    __shared__ short kls[64 * 64];
    __shared__ short vls[64 * 64];

    const int tid = threadIdx.x;
    const int l = tid & 63, w = tid >> 6;
    const int q = l & 31, hi = l >> 5;

    const int bid = blockIdx.x;
    const int b = bid & 7;
    const int j = bid >> 3;          // descending-qt enumeration (LPT)
    int qt = 0, ci = 0;
    {
        int acc = 0;
        for (int qq = 31; qq >= 0; --qq) {
            int nc = (2 * qq + 17) >> 4;
            if (j < acc + nc) { qt = qq; ci = j - acc; break; }
            acc += nc;
        }
    }
    const int nch = (2 * qt + 17) >> 4;
    int ntile = 2 * qt + 2 - 16 * ci;
    if (ntile > 16) ntile = 16;
    const int c0 = ci * 1024;

    const int q0w = qt * 128 + 32 * w;
    const int qr = q0w + q;
    const int lastg = (q0w + 31) >> 6;    // wave's diagonal tile (global idx)

    const unsigned short* qb = qg + ((long)b * TT + qr) * HD;
    short8 qf[4];
#pragma unroll
    for (int ki = 0; ki < 4; ++ki) qf[ki] = *(const short8*)(qb + 16 * ki + 8 * hi);

    f32x16 oacc[2] = {};
    float m = -INFINITY, lsum = 0.f;

    const unsigned short* kbase = kg + (long)b * TT * HD;
    const unsigned short* vbase = vtg + (long)b * HD * TT;

    short8 kst[2], vst[2];
#pragma unroll
    for (int i = 0; i < 2; ++i) {
        int slot = tid + 256 * i;
        int row = slot >> 3, bl = slot & 7;
        kst[i] = *(const short8*)(kbase + (long)(c0 + row) * HD + 8 * bl);
        vst[i] = *(const short8*)(vbase + (long)row * TT + c0 + 8 * bl);
    }

    for (int it = 0; it < ntile; ++it) {
        const int s0 = c0 + it * 64;
        const int gti = ci * 16 + it;
        __syncthreads();
#pragma unroll
        for (int i = 0; i < 2; ++i) {
            int slot = tid + 256 * i;
            int row = slot >> 3, bl = slot & 7;
            *(short8*)&kls[row * 64 + 8 * (bl ^ (row & 7))] = kst[i];
            *(short8*)&vls[row * 64 + 8 * (bl ^ (row & 7))] = vst[i];
        }
        __syncthreads();
        if (it + 1 < ntile) {
            const int s1 = s0 + 64;
#pragma unroll
            for (int i = 0; i < 2; ++i) {
                int slot = tid + 256 * i;
                int row = slot >> 3, bl = slot & 7;
                kst[i] = *(const short8*)(kbase + (long)(s1 + row) * HD + 8 * bl);
                vst[i] = *(const short8*)(vbase + (long)row * TT + s1 + 8 * bl);
            }
        }
        if (s0 > q0w + 31) continue;   // wave past causal range (barriers already done)

        const int nkt = (gti == lastg && (w & 1) == 0) ? 1 : 2;

        // S^T = K Q^T (q pre-scaled by 0.125 in proj)
        f32x16 sacc[2] = {};
#pragma unroll
        for (int kt = 0; kt < 2; ++kt) {
            if (kt < nkt) {
#pragma unroll
                for (int ki = 0; ki < 4; ++ki) {
                    int row = 32 * kt + q;
                    short8 kf = *(const short8*)&kls[row * 64 + 8 * ((2 * ki + hi) ^ (row & 7))];
                    sacc[kt] = __builtin_amdgcn_mfma_f32_32x32x16_bf16(kf, qf[ki], sacc[kt], 0, 0, 0);
                }
            }
        }

        // causal mask (diagonal tile only) + lane-local max
        float pmax = -INFINITY;
#pragma unroll
        for (int kt = 0; kt < 2; ++kt) {
            if (kt >= nkt) continue;
            if (gti == lastg) {
#pragma unroll
                for (int r = 0; r < 16; ++r) {
                    int kkg = s0 + 32 * kt + (r & 3) + 8 * (r >> 2) + 4 * hi;
                    if (kkg > qr) sacc[kt][r] = -INFINITY;
                    pmax = fmaxf(pmax, sacc[kt][r]);
                }
            } else {
#pragma unroll
                for (int r = 0; r < 16; ++r) pmax = fmaxf(pmax, sacc[kt][r]);
            }
        }
        pmax = fmaxf(pmax, __shfl_xor(pmax, 32, 64));
        if (__any(pmax > m)) {         // wave-uniform rescale skip (T13-style)
            float mn = fmaxf(m, pmax);
            float fac = __expf(m - mn);
            lsum *= fac;
            oacc[0] *= fac;
            oacc[1] *= fac;
            m = mn;
        }

        float rsum = 0.f;
        unsigned ulo[8], uhi[8];
#pragma unroll
        for (int kt = 0; kt < 2; ++kt) {
#pragma unroll
            for (int jj = 0; jj < 4; ++jj) {
                float p0 = 0.f, p1 = 0.f, p2 = 0.f, p3 = 0.f;
                if (kt < nkt) {
                    p0 = __expf(sacc[kt][4 * jj + 0] - m);
                    p1 = __expf(sacc[kt][4 * jj + 1] - m);
                    p2 = __expf(sacc[kt][4 * jj + 2] - m);
                    p3 = __expf(sacc[kt][4 * jj + 3] - m);
                    rsum += (p0 + p1) + (p2 + p3);
                }
                ulo[4 * kt + jj] = pack_bf2(p0, p1);
                uhi[4 * kt + jj] = pack_bf2(p2, p3);
            }
        }
        rsum += __shfl_xor(rsum, 32, 64);
        lsum += rsum;

        const int nks = 2 * nkt;
#pragma unroll
        for (int ks = 0; ks < 4; ++ks) {
            if (ks >= nks) continue;
            uint2v rlo = __builtin_amdgcn_permlane32_swap(ulo[2 * ks], ulo[2 * ks + 1], false, false);
            uint2v rhi = __builtin_amdgcn_permlane32_swap(uhi[2 * ks], uhi[2 * ks + 1], false, false);
            unsigned paw0 = rlo[0], paw1 = rhi[0], paw2 = rlo[1], paw3 = rhi[1];
            short8 pa;
            {
                uint2v t0v; t0v[0] = paw0; t0v[1] = paw1;
                uint2v t1v; t1v[0] = paw2; t1v[1] = paw3;
                short8 tmp;
                tmp[0] = (short)(paw0 & 0xffff); tmp[1] = (short)(paw0 >> 16);
                tmp[2] = (short)(paw1 & 0xffff); tmp[3] = (short)(paw1 >> 16);
                tmp[4] = (short)(paw2 & 0xffff); tmp[5] = (short)(paw2 >> 16);
                tmp[6] = (short)(paw3 & 0xffff); tmp[7] = (short)(paw3 >> 16);
                pa = tmp;
            }
#pragma unroll
            for (int dt = 0; dt < 2; ++dt) {
                int row = 32 * dt + q;
                short8 vf = *(const short8*)&vls[row * 64 + 8 * ((2 * ks + hi) ^ (row & 7))];
                oacc[dt] = __builtin_amdgcn_mfma_f32_32x32x16_bf16(vf, pa, oacc[dt], 0, 0, 0);
            }
        }
    }

    const int lr = 32 * w + q;
    if (nch == 1) {
        const float inv = 1.f / lsum;
        float* op = outg + ((long)b * TT + qr) * HD;
#pragma unroll
        for (int dt = 0; dt < 2; ++dt) {
#pragma unroll
            for (int jj = 0; jj < 4; ++jj) {
                f32x4 o4;
                o4[0] = oacc[dt][4 * jj + 0] * inv;
                o4[1] = oacc[dt][4 * jj + 1] * inv;
                o4[2] = oacc[dt][4 * jj + 2] * inv;
                o4[3] = oacc[dt][4 * jj + 3] * inv;
                *(f32x4*)(op + 32 * dt + 8 * jj + 4 * hi) = o4;
            }
        }
    } else {
        const float inv = lsum > 0.f ? 1.f / lsum : 0.f;
        unsigned short* po = Opart + ((long)(b * 80 + j) * 128 + lr) * 64;
#pragma unroll
        for (int dt = 0; dt < 2; ++dt) {
#pragma unroll
            for (int jj = 0; jj < 4; ++jj) {
                uint2v u;
                u[0] = pack_bf2(oacc[dt][4 * jj + 0] * inv, oacc[dt][4 * jj + 1] * inv);
                u[1] = pack_bf2(oacc[dt][4 * jj + 2] * inv, oacc[dt][4 * jj + 3] * inv);
                *(uint2v*)(po + 32 * dt + 8 * jj + 4 * hi) = u;
            }
        }
        ml[(long)(b * 80 + j) * 128 + lr] = make_float2(m, lsum);
    }
}

// ---------------- Kernel 3: combine partials (qt >= 8) ----------------
__global__ __launch_bounds__(256) void combine(
    const unsigned short* __restrict__ Opart,
    const float2* __restrict__ ml,
    float* __restrict__ outg)
{
    const int bid = blockIdx.x;            // 192 = 8b x 24qt
    const int b = bid & 7, qt = 8 + (bid >> 3);
    const int nc = (2 * qt + 17) >> 4;     // 2..4
    int jb = 0;
    for (int qq = 31; qq > qt; --qq) jb += (2 * qq + 17) >> 4;

    const int tid = threadIdx.x;
    const int row = tid >> 1, dh = (tid & 1) * 32;
    const long base = (long)(b * 80 + jb) * 128 + row;

    float mv[4], lv[4], M = -INFINITY;
#pragma unroll
    for (int c = 0; c < 4; ++c) {
        mv[c] = -INFINITY; lv[c] = 0.f;
        if (c < nc) {
            float2 t = ml[base + (long)c * 128];
            mv[c] = t.x; lv[c] = t.y;
            M = fmaxf(M, mv[c]);
        }
    }
    float L = 0.f, wt[4];
#pragma unroll
    for (int c = 0; c < 4; ++c) {
        wt[c] = (c < nc) ? lv[c] * __expf(mv[c] - M) : 0.f;
        L += wt[c];
    }
    float acc[32];
#pragma unroll
    for (int i = 0; i < 32; ++i) acc[i] = 0.f;
#pragma unroll
    for (int c = 0; c < 4; ++c) {
        if (c < nc && wt[c] > 0.f) {
            const short8* op = (const short8*)(Opart + (base + (long)c * 128) * 64 + dh);
#pragma unroll
            for (int i = 0; i < 4; ++i) {
                short8 v = op[i];
#pragma unroll
                for (int e = 0; e < 8; ++e)
                    acc[8 * i + e] += wt[c] * bf2f((unsigned short)v[e]);
            }
        }
    }
    const float invL = 1.f / L;
    float* dst = outg + ((long)b * TT + qt * 128 + row) * HD + dh;
#pragma unroll
    for (int i = 0; i < 8; ++i) {
        f32x4 o;
        o[0] = acc[4 * i + 0] * invL; o[1] = acc[4 * i + 1] * invL;
        o[2] = acc[4 * i + 2] * invL; o[3] = acc[4 * i + 3] * invL;
        *(f32x4*)(dst + 4 * i) = o;
    }
}

extern "C" void kernel_launch(void* const* d_in, const int* in_sizes, int n_in,
                              void* d_out, int out_size, void* d_ws, size_t ws_size,
                              hipStream_t stream) {
    const float* x  = (const float*)d_in[0];
    const float* Wk = (const float*)d_in[1];
    const float* Wq = (const float*)d_in[2];
    const float* Wv = (const float*)d_in[3];
    float* out = (float*)d_out;

    const long N = (long)BB * TT * HD;                    // 2,097,152
    unsigned short* q16 = (unsigned short*)d_ws;          // 4 MB
    unsigned short* k16 = q16 + N;                        // 4 MB
    unsigned short* vt16 = k16 + N;                       // 4 MB (V transposed [b][d][t])
    unsigned short* Opart = (unsigned short*)((char*)d_ws + 12 * 1024 * 1024);  // 10 MB
    float2* mlp = (float2*)((char*)d_ws + 23068672);      // 0.64 MB (ends 23.7 MB)

    qkv_proj_mfma<<<BB * TT / 128, 256, 0, stream>>>(x, Wk, Wq, Wv, q16, k16, vt16);
    attn_mfma<<<8 * 80, 256, 0, stream>>>(q16, k16, vt16, Opart, mlp, out);
    combine<<<8 * 24, 256, 0, stream>>>(Opart, mlp, out);
}

// Round 5
// 78.713 us; speedup vs baseline: 14.9093x; 1.0681x over previous
//
#include <hip/hip_runtime.h>
#include <hip/hip_bf16.h>
#include <math.h>

#define BB 8
#define TT 4096
#define HD 64

typedef __attribute__((ext_vector_type(8))) short short8;
typedef __attribute__((ext_vector_type(4))) float f32x4;
typedef __attribute__((ext_vector_type(16))) float f32x16;
typedef __attribute__((ext_vector_type(2))) unsigned int uint2v;
typedef __attribute__((ext_vector_type(4))) unsigned int uint4v;

#define LOG2E 1.44269504088896f

__device__ __forceinline__ unsigned short bfbits(float f) {
    return __builtin_bit_cast(unsigned short, __float2bfloat16(f));
}
__device__ __forceinline__ unsigned pack_bf2(float a, float b) {
    return (unsigned)bfbits(a) | ((unsigned)bfbits(b) << 16);
}
__device__ __forceinline__ float bf2f(unsigned short u) {
    unsigned v = (unsigned)u << 16;
    return __builtin_bit_cast(float, v);
}
__device__ __forceinline__ short8 cvt8(float4 a, float4 b, float sc) {
    short8 s;
    s[0] = (short)bfbits(a.x * sc); s[1] = (short)bfbits(a.y * sc);
    s[2] = (short)bfbits(a.z * sc); s[3] = (short)bfbits(a.w * sc);
    s[4] = (short)bfbits(b.x * sc); s[5] = (short)bfbits(b.y * sc);
    s[6] = (short)bfbits(b.z * sc); s[7] = (short)bfbits(b.w * sc);
    return s;
}

// ---------------- Kernel 1: MFMA QKV projection ----------------
// C[t,h'] = x·W'^T via mfma. Wq pre-scaled by 0.125*log2e (exp2-domain softmax).
// V computed swapped -> direct coalesced transposed stores [b][d][t].
__global__ __launch_bounds__(256) void qkv_proj_mfma(
    const float* __restrict__ x,
    const float* __restrict__ Wk, const float* __restrict__ Wq, const float* __restrict__ Wv,
    unsigned short* __restrict__ qo, unsigned short* __restrict__ ko,
    unsigned short* __restrict__ vto)
{
    __shared__ short lds[20480];
    short* xls = lds;
    short* wls = lds + 8192;

    const int tid = threadIdx.x;
    const int l = tid & 63, w = tid >> 6;
    const int hi = l >> 5, c31 = l & 31;
    const long t0 = (long)blockIdx.x * 128;
    const int b = (int)(t0 >> 12);
    const int tl0 = (int)(t0 & 4095);

#pragma unroll
    for (int i = 0; i < 4; ++i) {
        int slot = tid + 256 * i;
        int row = slot >> 3, bl = slot & 7;
        const float* xp = x + (t0 + row) * 64 + 8 * bl;
        float4 a = *(const float4*)xp;
        float4 bq = *(const float4*)(xp + 4);
        *(short8*)&xls[row * 64 + 8 * (bl ^ (row & 7))] = cvt8(a, bq, 1.f);
    }
#pragma unroll
    for (int i = 0; i < 6; ++i) {
        int slot = tid + 256 * i;
        int row = slot >> 3, bl = slot & 7;
        const float* wp;
        float sc;
        if (row < 64)       { wp = Wq + row * 64;         sc = 0.125f * LOG2E; }
        else if (row < 128) { wp = Wk + (row - 64) * 64;  sc = 1.f; }
        else                { wp = Wv + (row - 128) * 64; sc = 1.f; }
        wp += 8 * bl;
        float4 a = *(const float4*)wp;
        float4 bq = *(const float4*)(wp + 4);
        *(short8*)&wls[row * 64 + 8 * (bl ^ (row & 7))] = cvt8(a, bq, sc);
    }
    __syncthreads();

    short8 xf[4];
#pragma unroll
    for (int ki = 0; ki < 4; ++ki) {
        int row = 32 * w + c31;
        xf[ki] = *(const short8*)&xls[row * 64 + 8 * ((2 * ki + hi) ^ (row & 7))];
    }
    f32x16 cqk[4] = {};
#pragma unroll
    for (int nt = 0; nt < 4; ++nt) {
#pragma unroll
        for (int ki = 0; ki < 4; ++ki) {
            int row = 32 * nt + c31;
            short8 wf = *(const short8*)&wls[row * 64 + 8 * ((2 * ki + hi) ^ (row & 7))];
            cqk[nt] = __builtin_amdgcn_mfma_f32_32x32x16_bf16(xf[ki], wf, cqk[nt], 0, 0, 0);
        }
    }
    f32x16 cv[2] = {};
#pragma unroll
    for (int rt = 0; rt < 2; ++rt) {
#pragma unroll
        for (int ki = 0; ki < 4; ++ki) {
            int row = 128 + 32 * rt + c31;
            short8 wf = *(const short8*)&wls[row * 64 + 8 * ((2 * ki + hi) ^ (row & 7))];
            cv[rt] = __builtin_amdgcn_mfma_f32_32x32x16_bf16(wf, xf[ki], cv[rt], 0, 0, 0);
        }
    }
#pragma unroll
    for (int rt = 0; rt < 2; ++rt) {
#pragma unroll
        for (int r = 0; r < 16; ++r) {
            int h = 32 * rt + (r & 3) + 8 * (r >> 2) + 4 * hi;
            vto[((long)b * 64 + h) * 4096 + tl0 + 32 * w + c31] = bfbits(cv[rt][r]);
        }
    }

    __syncthreads();
    short* cb = lds;
#pragma unroll
    for (int nt = 0; nt < 4; ++nt) {
#pragma unroll
        for (int r = 0; r < 16; ++r) {
            int trow = 32 * w + (r & 3) + 8 * (r >> 2) + 4 * hi;
            cb[trow * 136 + 32 * nt + c31] = (short)bfbits(cqk[nt][r]);
        }
    }
    __syncthreads();
    {
        int row = tid >> 1, seg = tid & 1;
        const short8* cp = (const short8*)&cb[row * 136 + seg * 64];
        unsigned short* dst = (seg == 0 ? qo : ko) + (t0 + row) * 64;
#pragma unroll
        for (int i = 0; i < 8; ++i) ((short8*)dst)[i] = cp[i];
    }
}

// ---------------- Kernel 2: MFMA flash attention, split-s, 2-phase pipeline ----------------
// Double-buffered LDS filled via global_load_lds (width 16) with pre-swizzled
// global source + linear LDS dest (rule #21); one barrier per KV tile; loads
// drain a full compute-phase after issue. Swapped QK^T -> lane-local softmax
// in exp2 domain; permlane P->A; T5 setprio around MFMA clusters.
__global__ __launch_bounds__(256, 4) void attn_mfma(
    const unsigned short* __restrict__ qg,
    const unsigned short* __restrict__ kg,
    const unsigned short* __restrict__ vtg,
    unsigned short* __restrict__ Opart,
    float2* __restrict__ ml,
    float* __restrict__ outg)
{
    __shared__ short kls[2][4096];   // K[s][d] tiles, 16B-block XOR swizzle on read
    __shared__ short vls[2][4096];   // V^T[d][s] tiles

    const int tid = threadIdx.x;
    const int l = tid & 63, w = tid >> 6;
    const int q = l & 31, hi = l >> 5;

    const int bid = blockIdx.x;
    const int b = bid & 7;
    const int j = bid >> 3;
    int qt = 0, ci = 0;
    {
        int acc = 0;
        for (int qq = 31; qq >= 0; --qq) {
            int nc = (2 * qq + 17) >> 4;
            if (j < acc + nc) { qt = qq; ci = j - acc; break; }
            acc += nc;
        }
    }
    const int nch = (2 * qt + 17) >> 4;
    int ntile = 2 * qt + 2 - 16 * ci;
    if (ntile > 16) ntile = 16;
    const int c0 = ci * 1024;

    const int q0w = qt * 128 + 32 * w;
    const int qr = q0w + q;
    const int lastg = (q0w + 31) >> 6;

    const unsigned short* qb = qg + ((long)b * TT + qr) * HD;
    short8 qf[4];
#pragma unroll
    for (int ki = 0; ki < 4; ++ki) qf[ki] = *(const short8*)(qb + 16 * ki + 8 * hi);

    f32x16 oacc[2] = {};
    float m = -INFINITY, lsum = 0.f;

    const unsigned short* kbase = kg + (long)b * TT * HD;
    const unsigned short* vbase = vtg + (long)b * HD * TT;

    // staging geometry: slot = 256c + 64w + lane; row = slot>>3, bl = slot&7.
    // LDS linear at slot*16B; global source pre-swizzled: bl' = bl ^ (row&7).
    const int r8 = l >> 3;                 // row&7 for this lane
    const int blsw = (l & 7) ^ r8;         // pre-swizzled 16B block
    const long koff0 = (long)(8 * w + r8) * HD + 8 * blsw;        // + s*HD per tile, + 32*HD per chunk c
    const long voff0 = (long)(8 * w + r8) * TT + 8 * blsw;        // + s per tile, + 32*TT per chunk c

#define STAGE(cur_, s_) do {                                                            \
    _Pragma("unroll")                                                                   \
    for (int c_ = 0; c_ < 2; ++c_) {                                                    \
        const unsigned short* kp_ = kbase + (long)(s_) * HD + koff0 + (long)c_ * 32 * HD; \
        const unsigned short* vp_ = vbase + (s_) + voff0 + (long)c_ * 32 * TT;          \
        short* kd_ = &kls[cur_][2048 * c_ + 512 * w];                                   \
        short* vd_ = &vls[cur_][2048 * c_ + 512 * w];                                   \
        __builtin_amdgcn_global_load_lds((const __attribute__((address_space(1))) void*)kp_, \
                                         (__attribute__((address_space(3))) void*)kd_, 16, 0, 0); \
        __builtin_amdgcn_global_load_lds((const __attribute__((address_space(1))) void*)vp_, \
                                         (__attribute__((address_space(3))) void*)vd_, 16, 0, 0); \
    }                                                                                   \
} while (0)

    int cur = 0;
    STAGE(0, c0);

    for (int it = 0; it < ntile; ++it) {
        const int s0 = c0 + (it << 6);
        __syncthreads();                 // vmcnt(0)+barrier: buf[cur] ready, buf[cur^1] free
        if (it + 1 < ntile) STAGE(cur ^ 1, s0 + 64);

        if (s0 <= q0w + 31) {
            const int gti = ci * 16 + it;
            const int nkt = (gti == lastg && (w & 1) == 0) ? 1 : 2;
            const int qs7 = q & 7;
            const short* kb_ = kls[cur];
            const short* vb_ = vls[cur];

            // ---- S^T = K Q^T (exp2-domain: q pre-scaled by 0.125*log2e) ----
            f32x16 sacc[2] = {};
            __builtin_amdgcn_s_setprio(1);
#pragma unroll
            for (int kt = 0; kt < 2; ++kt) {
                if (kt < nkt) {
#pragma unroll
                    for (int ki = 0; ki < 4; ++ki) {
                        int row = 32 * kt + q;
                        short8 kf = *(const short8*)&kb_[row * 64 + 8 * ((2 * ki + hi) ^ qs7)];
                        sacc[kt] = __builtin_amdgcn_mfma_f32_32x32x16_bf16(kf, qf[ki], sacc[kt], 0, 0, 0);
                    }
                }
            }
            __builtin_amdgcn_s_setprio(0);

            // ---- causal mask (diagonal tile only) + lane-local max ----
            float pmax = -INFINITY;
#pragma unroll
            for (int kt = 0; kt < 2; ++kt) {
                if (kt >= nkt) continue;
                if (gti == lastg) {
#pragma unroll
                    for (int r = 0; r < 16; ++r) {
                        int kkg = s0 + 32 * kt + (r & 3) + 8 * (r >> 2) + 4 * hi;
                        if (kkg > qr) sacc[kt][r] = -INFINITY;
                        pmax = fmaxf(pmax, sacc[kt][r]);
                    }
                } else {
#pragma unroll
                    for (int r = 0; r < 16; ++r) pmax = fmaxf(pmax, sacc[kt][r]);
                }
            }
            pmax = fmaxf(pmax, __shfl_xor(pmax, 32, 64));
            if (__any(pmax > m)) {       // defer-rescale (T13-style)
                float mn = fmaxf(m, pmax);
                float fac = exp2f(m - mn);
                lsum *= fac;
                oacc[0] *= fac;
                oacc[1] *= fac;
                m = mn;
            }

            // ---- P = exp2(S - m), pack bf16 ----
            float rsum = 0.f;
            unsigned ulo[8], uhi[8];
#pragma unroll
            for (int kt = 0; kt < 2; ++kt) {
#pragma unroll
                for (int jj = 0; jj < 4; ++jj) {
                    float p0 = 0.f, p1 = 0.f, p2 = 0.f, p3 = 0.f;
                    if (kt < nkt) {
                        p0 = exp2f(sacc[kt][4 * jj + 0] - m);
                        p1 = exp2f(sacc[kt][4 * jj + 1] - m);
                        p2 = exp2f(sacc[kt][4 * jj + 2] - m);
                        p3 = exp2f(sacc[kt][4 * jj + 3] - m);
                        rsum += (p0 + p1) + (p2 + p3);
                    }
                    ulo[4 * kt + jj] = pack_bf2(p0, p1);
                    uhi[4 * kt + jj] = pack_bf2(p2, p3);
                }
            }
            rsum += __shfl_xor(rsum, 32, 64);
            lsum += rsum;

            // ---- O^T += V^T P (P -> A-frag via permlane32_swap) ----
            const int nks = 2 * nkt;
#pragma unroll
            for (int ks = 0; ks < 4; ++ks) {
                if (ks >= nks) continue;
                uint2v rlo = __builtin_amdgcn_permlane32_swap(ulo[2 * ks], ulo[2 * ks + 1], false, false);
                uint2v rhi = __builtin_amdgcn_permlane32_swap(uhi[2 * ks], uhi[2 * ks + 1], false, false);
                uint4v paw;
                paw[0] = rlo[0]; paw[1] = rhi[0]; paw[2] = rlo[1]; paw[3] = rhi[1];
                short8 pa = __builtin_bit_cast(short8, paw);
                __builtin_amdgcn_s_setprio(1);
#pragma unroll
                for (int dt = 0; dt < 2; ++dt) {
                    int row = 32 * dt + q;
                    short8 vf = *(const short8*)&vb_[row * 64 + 8 * ((2 * ks + hi) ^ qs7)];
                    oacc[dt] = __builtin_amdgcn_mfma_f32_32x32x16_bf16(vf, pa, oacc[dt], 0, 0, 0);
                }
                __builtin_amdgcn_s_setprio(0);
            }
        }
        cur ^= 1;
    }
#undef STAGE

    const int lr = 32 * w + q;
    if (nch == 1) {
        const float inv = 1.f / lsum;
        float* op = outg + ((long)b * TT + qr) * HD;
#pragma unroll
        for (int dt = 0; dt < 2; ++dt) {
#pragma unroll
            for (int jj = 0; jj < 4; ++jj) {
                f32x4 o4;
                o4[0] = oacc[dt][4 * jj + 0] * inv;
                o4[1] = oacc[dt][4 * jj + 1] * inv;
                o4[2] = oacc[dt][4 * jj + 2] * inv;
                o4[3] = oacc[dt][4 * jj + 3] * inv;
                *(f32x4*)(op + 32 * dt + 8 * jj + 4 * hi) = o4;
            }
        }
    } else {
        const float inv = lsum > 0.f ? 1.f / lsum : 0.f;
        unsigned short* po = Opart + ((long)(b * 80 + j) * 128 + lr) * 64;
#pragma unroll
        for (int dt = 0; dt < 2; ++dt) {
#pragma unroll
            for (int jj = 0; jj < 4; ++jj) {
                uint2v u;
                u[0] = pack_bf2(oacc[dt][4 * jj + 0] * inv, oacc[dt][4 * jj + 1] * inv);
                u[1] = pack_bf2(oacc[dt][4 * jj + 2] * inv, oacc[dt][4 * jj + 3] * inv);
                *(uint2v*)(po + 32 * dt + 8 * jj + 4 * hi) = u;
            }
        }
        ml[(long)(b * 80 + j) * 128 + lr] = make_float2(m, lsum);
    }
}

// ---------------- Kernel 3: combine partials (qt >= 8; m in exp2 domain) ----------------
__global__ __launch_bounds__(256) void combine(
    const unsigned short* __restrict__ Opart,
    const float2* __restrict__ ml,
    float* __restrict__ outg)
{
    const int bid = blockIdx.x;
    const int b = bid & 7, qt = 8 + (bid >> 3);
    const int nc = (2 * qt + 17) >> 4;
    int jb = 0;
    for (int qq = 31; qq > qt; --qq) jb += (2 * qq + 17) >> 4;

    const int tid = threadIdx.x;
    const int row = tid >> 1, dh = (tid & 1) * 32;
    const long base = (long)(b * 80 + jb) * 128 + row;

    float mv[4], lv[4], M = -INFINITY;
#pragma unroll
    for (int c = 0; c < 4; ++c) {
        mv[c] = -INFINITY; lv[c] = 0.f;
        if (c < nc) {
            float2 t = ml[base + (long)c * 128];
            mv[c] = t.x; lv[c] = t.y;
            M = fmaxf(M, mv[c]);
        }
    }
    float L = 0.f, wt[4];
#pragma unroll
    for (int c = 0; c < 4; ++c) {
        wt[c] = (c < nc) ? lv[c] * exp2f(mv[c] - M) : 0.f;
        L += wt[c];
    }
    float acc[32];
#pragma unroll
    for (int i = 0; i < 32; ++i) acc[i] = 0.f;
#pragma unroll
    for (int c = 0; c < 4; ++c) {
        if (c < nc && wt[c] > 0.f) {
            const short8* op = (const short8*)(Opart + (base + (long)c * 128) * 64 + dh);
#pragma unroll
            for (int i = 0; i < 4; ++i) {
                short8 v = op[i];
#pragma unroll
                for (int e = 0; e < 8; ++e)
                    acc[8 * i + e] += wt[c] * bf2f((unsigned short)v[e]);
            }
        }
    }
    const float invL = 1.f / L;
    float* dst = outg + ((long)b * TT + qt * 128 + row) * HD + dh;
#pragma unroll
    for (int i = 0; i < 8; ++i) {
        f32x4 o;
        o[0] = acc[4 * i + 0] * invL; o[1] = acc[4 * i + 1] * invL;
        o[2] = acc[4 * i + 2] * invL; o[3] = acc[4 * i + 3] * invL;
        *(f32x4*)(dst + 4 * i) = o;
    }
}

extern "C" void kernel_launch(void* const* d_in, const int* in_sizes, int n_in,
                              void* d_out, int out_size, void* d_ws, size_t ws_size,
                              hipStream_t stream) {
    const float* x  = (const float*)d_in[0];
    const float* Wk = (const float*)d_in[1];
    const float* Wq = (const float*)d_in[2];
    const float* Wv = (const float*)d_in[3];
    float* out = (float*)d_out;

    const long N = (long)BB * TT * HD;
    unsigned short* q16 = (unsigned short*)d_ws;
    unsigned short* k16 = q16 + N;
    unsigned short* vt16 = k16 + N;
    unsigned short* Opart = (unsigned short*)((char*)d_ws + 12 * 1024 * 1024);
    float2* mlp = (float2*)((char*)d_ws + 23068672);

    qkv_proj_mfma<<<BB * TT / 128, 256, 0, stream>>>(x, Wk, Wq, Wv, q16, k16, vt16);
    attn_mfma<<<8 * 80, 256, 0, stream>>>(q16, k16, vt16, Opart, mlp, out);
    combine<<<8 * 24, 256, 0, stream>>>(Opart, mlp, out);
}